// Round 1
// baseline (21911.684 us; speedup 1.0000x reference)
//
#include <hip/hip_runtime.h>
#include <hip/hip_bf16.h>

// GRU, T=2048, B=64, D=H=512, fp32.
// Strategy:
//   1) prep_weights: split fp32 W[512,1024] into x-part / h-part, cast bf16.
//   2) xpre_gemm:    bf16 MFMA GEMM precomputing all x-side gate pre-acts
//                    (+bias) into fp32 Xbuf (runtime-chunked to fit ws).
//   3) gru_rec:      persistent-ish 128-block kernel; 4 row-clusters x 32
//                    column-slices; weight slices LDS-resident; per-step
//                    cross-block exchange of h and r*h (bf16) via agent-scope
//                    atomics + monotonic counters. State h kept fp32 in regs.

#define T_STEPS 2048
#define BATCH   64
#define HID     512

typedef __attribute__((ext_vector_type(8))) short short8;
typedef __attribute__((ext_vector_type(8))) unsigned short ushort8;
typedef __attribute__((ext_vector_type(4))) float f32x4;

__device__ __forceinline__ unsigned short f2bf(float f) {
  __hip_bfloat16 h = __float2bfloat16(f);
  return *reinterpret_cast<unsigned short*>(&h);
}
__device__ __forceinline__ float bf2f(unsigned short u) {
  __hip_bfloat16 h = *reinterpret_cast<__hip_bfloat16*>(&u);
  return __bfloat162float(h);
}

// ---------------------------------------------------------------- prep
__global__ __launch_bounds__(256) void prep_weights(
    const float* __restrict__ Wr, const float* __restrict__ br,
    const float* __restrict__ Wz, const float* __restrict__ bz,
    const float* __restrict__ Wg, const float* __restrict__ bg,
    unsigned short* __restrict__ whb,   // [3][512][512] bf16 (h-part)
    unsigned short* __restrict__ wxb,   // [1536][512]   bf16 (x-part)
    float* __restrict__ bias)           // [1536]
{
  int g = blockIdx.x >> 9;        // 0..2
  int n = blockIdx.x & 511;       // output row
  const float* W  = (g == 0) ? Wr : (g == 1) ? Wz : Wg;
  const float* bs = (g == 0) ? br : (g == 1) ? bz : bg;
  const float* row = W + (size_t)n * 1024;
  size_t obase = ((size_t)g * 512 + n) * 512;
  for (int k = threadIdx.x; k < 512; k += 256) {
    wxb[obase + k] = f2bf(row[k]);         // x-part: cols [0,512)
    whb[obase + k] = f2bf(row[512 + k]);   // h-part: cols [512,1024)
  }
  if (threadIdx.x == 0) bias[g * 512 + n] = bs[n];
}

// ---------------------------------------------------------------- x GEMM
// Xbuf[row][gate*512+col] = x_row . Wx[gate][col] + bias  (fp32 out)
// 128x128 tile, BK=32, bf16 16x16x32 MFMA, 4 waves in 2x2.
__global__ __launch_bounds__(256) void xpre_gemm(
    const float* __restrict__ x,              // [rows][512]
    const unsigned short* __restrict__ wxb,   // [1536][512]
    const float* __restrict__ bias,           // [1536]
    float* __restrict__ xbuf)                 // [rows][1536]
{
  __shared__ __align__(16) unsigned short aT[128][40];  // +8 pad: 2-way banks
  __shared__ __align__(16) unsigned short bT[128][40];
  const int tid = threadIdx.x;
  const int bm = blockIdx.x, bn = blockIdx.y;
  const int wv = tid >> 6, lane = tid & 63, l15 = lane & 15, quad = lane >> 4;
  const int m_off = (wv & 1) * 64, n_off = (wv >> 1) * 64;
  f32x4 acc[4][4] = {};
  const int r = tid >> 1, ks = (tid & 1) * 16;
  const float* ag = x + (size_t)(bm * 128 + r) * 512 + ks;
  const unsigned short* bgp = wxb + (size_t)(bn * 128 + r) * 512 + ks;
  for (int kb = 0; kb < 16; ++kb) {
    const f32x4* af4 = (const f32x4*)(ag + kb * 32);
    f32x4 v0 = af4[0], v1 = af4[1], v2 = af4[2], v3 = af4[3];
    ushort8 u0 = { f2bf(v0[0]), f2bf(v0[1]), f2bf(v0[2]), f2bf(v0[3]),
                   f2bf(v1[0]), f2bf(v1[1]), f2bf(v1[2]), f2bf(v1[3]) };
    ushort8 u1 = { f2bf(v2[0]), f2bf(v2[1]), f2bf(v2[2]), f2bf(v2[3]),
                   f2bf(v3[0]), f2bf(v3[1]), f2bf(v3[2]), f2bf(v3[3]) };
    *(ushort8*)&aT[r][ks]     = u0;
    *(ushort8*)&aT[r][ks + 8] = u1;
    const ushort8* bv = (const ushort8*)(bgp + kb * 32);
    *(ushort8*)&bT[r][ks]     = bv[0];
    *(ushort8*)&bT[r][ks + 8] = bv[1];
    __syncthreads();
    short8 afr[4], bfr[4];
    #pragma unroll
    for (int mt = 0; mt < 4; ++mt)
      afr[mt] = *(const short8*)&aT[m_off + mt * 16 + l15][quad * 8];
    #pragma unroll
    for (int nt = 0; nt < 4; ++nt)
      bfr[nt] = *(const short8*)&bT[n_off + nt * 16 + l15][quad * 8];
    #pragma unroll
    for (int mt = 0; mt < 4; ++mt)
      #pragma unroll
      for (int nt = 0; nt < 4; ++nt)
        acc[mt][nt] = __builtin_amdgcn_mfma_f32_16x16x32_bf16(
            afr[mt], bfr[nt], acc[mt][nt], 0, 0, 0);
    __syncthreads();
  }
  #pragma unroll
  for (int nt = 0; nt < 4; ++nt) {
    int n_g = bn * 128 + n_off + nt * 16 + l15;
    float bv = bias[n_g];
    #pragma unroll
    for (int mt = 0; mt < 4; ++mt) {
      int m_g = bm * 128 + m_off + mt * 16 + quad * 4;
      #pragma unroll
      for (int i = 0; i < 4; ++i)
        xbuf[(size_t)(m_g + i) * 1536 + n_g] = acc[mt][nt][i] + bv;
    }
  }
}

// ---------------------------------------------------------------- recurrence
// 128 blocks x 128 threads. cluster c = bid&3 (rows c*16..+16),
// slice s = bid>>2 (cols s*16..+16). wave0: z then g + h update;
// wave1: r then r*h broadcast. Weight slices (3 x 16 x 512 bf16) in LDS.
// Exchange h / r*h per step via bf16 buffers (parity double-buffered) +
// monotonic per-cluster counters (32 posts per phase).
__global__ __launch_bounds__(128) void gru_rec(
    const float* __restrict__ xbuf,           // [cs*64][1536] fp32
    const unsigned short* __restrict__ whb,   // [3][512][512] bf16
    float* __restrict__ dout,
    float* __restrict__ hstateF,              // [64][512] fp32 chunk carry
    unsigned short* hbuf, unsigned short* rhbuf,  // [2][64][512] bf16
    unsigned int* cnt, int t0, int cs)
{
  const int tid = threadIdx.x;
  const int bid = blockIdx.x;
  const int c = bid & 3;
  const int s = bid >> 2;
  const int wv = tid >> 6, lane = tid & 63, l15 = lane & 15, quad = lane >> 4;
  const int n_glob = s * 16 + l15;   // column for B-frag n and C/D col
  const int m_base = quad * 4;       // C/D rows = quad*4 + i
  const int row0 = c * 16;
  __shared__ __align__(16) unsigned short wlds[3][16][520];  // 48.8 KB

  for (int v = tid; v < 3 * 16 * 64; v += 128) {   // ushort8 granules
    int g  = v >> 10;
    int rr = (v >> 6) & 15;
    int kv = (v & 63) * 8;
    *(ushort8*)&wlds[g][rr][kv] =
        *(const ushort8*)&whb[((size_t)g * 512 + s * 16 + rr) * 512 + kv];
  }

  float hz[4] = {0.f, 0.f, 0.f, 0.f};   // fp32 own-tile state (wave0)
  if (t0 > 0 && wv == 0) {
    #pragma unroll
    for (int i = 0; i < 4; ++i)
      hz[i] = hstateF[(size_t)(row0 + m_base + i) * 512 + n_glob];
  }
  __syncthreads();

  unsigned int* rhc = cnt + c * 32;         // + parity*16 (64B lines)
  unsigned int* hc  = cnt + 128 + c * 32;   // + parity*16

  for (int t = t0; t < t0 + cs; ++t) {
    const int tl = t - t0;
    const int p = t & 1;
    const unsigned int target = (unsigned int)((t + 1) >> 1) * 32u;

    // prefetch x-side pre-activations (overlaps the h wait)
    const float* xrow = xbuf + (size_t)(tl * 64 + row0 + m_base) * 1536 + n_glob;
    float xa[4], xg[4] = {0.f, 0.f, 0.f, 0.f};
    if (wv == 0) {
      #pragma unroll
      for (int i = 0; i < 4; ++i) {
        xa[i] = xrow[(size_t)i * 1536 + 512];    // Xz
        xg[i] = xrow[(size_t)i * 1536 + 1024];   // Xg
      }
    } else {
      #pragma unroll
      for (int i = 0; i < 4; ++i) xa[i] = xrow[(size_t)i * 1536];  // Xr
    }

    if (t > 0) {  // wait for full h_t of our cluster
      if (lane == 0) {
        while (__hip_atomic_load(&hc[p * 16], __ATOMIC_RELAXED,
                                 __HIP_MEMORY_SCOPE_AGENT) < target)
          __builtin_amdgcn_s_sleep(2);
        (void)__hip_atomic_load(&hc[p * 16], __ATOMIC_ACQUIRE,
                                __HIP_MEMORY_SCOPE_AGENT);
      }
      __syncthreads();
    }

    // phase 1: wave0 -> z (gate 1), wave1 -> r (gate 0)
    f32x4 acc = {0.f, 0.f, 0.f, 0.f};
    const unsigned short* hbase = hbuf + (size_t)p * BATCH * 512;
    if (t > 0) {
      const int g1 = (wv == 0) ? 1 : 0;
      short8 afr[16];
      #pragma unroll
      for (int kb = 0; kb < 16; ++kb)
        afr[kb] = *(const short8*)&hbase[(size_t)(row0 + l15) * 512 + kb * 32 + quad * 8];
      f32x4 acc2 = {0.f, 0.f, 0.f, 0.f};
      #pragma unroll
      for (int kb = 0; kb < 16; kb += 2) {  // 2 chains for MFMA ILP
        acc  = __builtin_amdgcn_mfma_f32_16x16x32_bf16(afr[kb],
                 *(const short8*)&wlds[g1][l15][kb * 32 + quad * 8], acc, 0, 0, 0);
        acc2 = __builtin_amdgcn_mfma_f32_16x16x32_bf16(afr[kb + 1],
                 *(const short8*)&wlds[g1][l15][(kb + 1) * 32 + quad * 8], acc2, 0, 0, 0);
      }
      #pragma unroll
      for (int i = 0; i < 4; ++i) acc[i] += acc2[i];
    }

    float zv[4];
    if (wv == 0) {
      #pragma unroll
      for (int i = 0; i < 4; ++i)
        zv[i] = 1.f / (1.f + __expf(-(acc[i] + xa[i])));
    } else {
      #pragma unroll
      for (int i = 0; i < 4; ++i) {
        float rv  = 1.f / (1.f + __expf(-(acc[i] + xa[i])));
        float hvf = (t > 0)
            ? bf2f(hbase[(size_t)(row0 + m_base + i) * 512 + n_glob]) : 0.f;
        __hip_atomic_store(
            &rhbuf[(size_t)p * BATCH * 512 + (size_t)(row0 + m_base + i) * 512 + n_glob],
            f2bf(rv * hvf), __ATOMIC_RELAXED, __HIP_MEMORY_SCOPE_AGENT);
      }
    }

    // phase 2: exchange r*h, then wave0 computes g and h update
    f32x4 accg = {0.f, 0.f, 0.f, 0.f};
    if (t > 0) {
      __syncthreads();   // drains vmcnt -> rh stores globally visible
      if (tid == 0)
        __hip_atomic_fetch_add(&rhc[p * 16], 1u, __ATOMIC_RELAXED,
                               __HIP_MEMORY_SCOPE_AGENT);
      if (lane == 0) {
        while (__hip_atomic_load(&rhc[p * 16], __ATOMIC_RELAXED,
                                 __HIP_MEMORY_SCOPE_AGENT) < target)
          __builtin_amdgcn_s_sleep(2);
        (void)__hip_atomic_load(&rhc[p * 16], __ATOMIC_ACQUIRE,
                                __HIP_MEMORY_SCOPE_AGENT);
      }
      __syncthreads();
      if (wv == 0) {
        const unsigned short* rbase = rhbuf + (size_t)p * BATCH * 512;
        short8 afr[16];
        #pragma unroll
        for (int kb = 0; kb < 16; ++kb)
          afr[kb] = *(const short8*)&rbase[(size_t)(row0 + l15) * 512 + kb * 32 + quad * 8];
        f32x4 acc2 = {0.f, 0.f, 0.f, 0.f};
        #pragma unroll
        for (int kb = 0; kb < 16; kb += 2) {
          accg = __builtin_amdgcn_mfma_f32_16x16x32_bf16(afr[kb],
                   *(const short8*)&wlds[2][l15][kb * 32 + quad * 8], accg, 0, 0, 0);
          acc2 = __builtin_amdgcn_mfma_f32_16x16x32_bf16(afr[kb + 1],
                   *(const short8*)&wlds[2][l15][(kb + 1) * 32 + quad * 8], acc2, 0, 0, 0);
        }
        #pragma unroll
        for (int i = 0; i < 4; ++i) accg[i] += acc2[i];
      }
    }

    if (wv == 0) {
      #pragma unroll
      for (int i = 0; i < 4; ++i) {
        float pre = accg[i] + xg[i];
        float e  = __expf(-2.f * fabsf(pre));   // overflow-safe tanh
        float th = (1.f - e) / (1.f + e);
        th = (pre < 0.f) ? -th : th;
        float hn = zv[i] * hz[i] + (1.f - zv[i]) * th;
        hz[i] = hn;
        size_t ridx = (size_t)(row0 + m_base + i) * 512 + n_glob;
        dout[(size_t)t * BATCH * 512 + ridx] = hn;
        __hip_atomic_store(&hbuf[(size_t)((t + 1) & 1) * BATCH * 512 + ridx],
                           f2bf(hn), __ATOMIC_RELAXED, __HIP_MEMORY_SCOPE_AGENT);
        if (t == T_STEPS - 1)
          dout[(size_t)T_STEPS * BATCH * 512 + ridx] = hn;   // h_final
        if (t == t0 + cs - 1)
          hstateF[ridx] = hn;                                 // chunk carry
      }
    }
    __syncthreads();   // drains h stores before signaling
    if (tid == 0)
      __hip_atomic_fetch_add(&hc[((t + 1) & 1) * 16], 1u, __ATOMIC_RELAXED,
                             __HIP_MEMORY_SCOPE_AGENT);
  }
}

// ---------------------------------------------------------------- launch
extern "C" void kernel_launch(void* const* d_in, const int* in_sizes, int n_in,
                              void* d_out, int out_size, void* d_ws, size_t ws_size,
                              hipStream_t stream) {
  const float* x  = (const float*)d_in[0];
  const float* Wr = (const float*)d_in[1];
  const float* br = (const float*)d_in[2];
  const float* Wz = (const float*)d_in[3];
  const float* bz = (const float*)d_in[4];
  const float* Wg = (const float*)d_in[5];
  const float* bg = (const float*)d_in[6];
  float* out = (float*)d_out;
  char* ws = (char*)d_ws;

  // ws layout (256B-aligned offsets)
  unsigned int* cnt      = (unsigned int*)(ws + 0);         // 4 KB counters
  float* bias            = (float*)(ws + 4096);             // 6 KB
  float* hstateF         = (float*)(ws + 10240);            // 128 KB
  unsigned short* hbuf   = (unsigned short*)(ws + 141312);  // 128 KB
  unsigned short* rhbuf  = (unsigned short*)(ws + 272384);  // 128 KB
  unsigned short* whb    = (unsigned short*)(ws + 403456);  // 1.5 MB
  unsigned short* wxb    = (unsigned short*)(ws + 1976320); // 1.5 MB
  float* xbuf            = (float*)(ws + 3549184);          // cs*64*1536*4

  int cs = T_STEPS;   // largest chunk of timesteps whose Xbuf fits in ws
  while (cs > 8 &&
         3549184ull + (unsigned long long)cs * 64 * 1536 * 4 >
             (unsigned long long)ws_size)
    cs >>= 1;

  hipMemsetAsync(cnt, 0, 4096, stream);   // counters start at 0 each call
  prep_weights<<<1536, 256, 0, stream>>>(Wr, br, Wz, bz, Wg, bg, whb, wxb, bias);
  for (int t0 = 0; t0 < T_STEPS; t0 += cs) {
    xpre_gemm<<<dim3((cs * 64) / 128, 12), 256, 0, stream>>>(
        x + (size_t)t0 * 64 * 512, wxb, bias, xbuf);
    gru_rec<<<128, 128, 0, stream>>>(xbuf, whb, out, hstateF, hbuf, rhbuf,
                                     cnt, t0, cs);
  }
}